// Round 4
// baseline (139.677 us; speedup 1.0000x reference)
//
#include <hip/hip_runtime.h>
#include <hip/hip_bf16.h>
#include <math.h>

#define BB 8
#define SS 2048
#define HH 256
#define NHH 4
#define DD 64
#define MROWS (BB*SS)   // 16384
#define LOG2E 1.44269504f

typedef unsigned short u16;
typedef unsigned int   u32;
typedef __attribute__((ext_vector_type(8))) short bf16x8;
typedef __attribute__((ext_vector_type(4))) float f32x4;
typedef __attribute__((ext_vector_type(8))) u16   u16x8;
typedef __attribute__((ext_vector_type(4))) u16   u16x4;

__device__ inline u16 f2bf(float f) {
    union { float f; u32 u; } v; v.f = f;
    u32 r = v.u + 0x7fffu + ((v.u >> 16) & 1u);   // RNE
    return (u16)(r >> 16);
}
__device__ inline u16 f2bf_n(float f) {            // native cast (m240)
    __hip_bfloat16 h = __float2bfloat16(f);
    return *(u16*)&h;
}
__device__ inline float bf2f(u16 h) {
    union { u32 u; float f; } v; v.u = (u32)h << 16; return v.f;
}
__device__ inline float fexp2(float x) {
#if __has_builtin(__builtin_amdgcn_exp2f)
    return __builtin_amdgcn_exp2f(x);
#else
    return __expf(x * 0.6931471806f);
#endif
}
__device__ inline void gload16(const u16* g, u16* l) {
    __builtin_amdgcn_global_load_lds(
        (const __attribute__((address_space(1))) u32*)g,
        (__attribute__((address_space(3))) u32*)l, 16, 0, 0);
}

// ---------------------------------------------------------------------------
// mixed = bf16(inp+attr+pos); inpb = bf16(inp)
__global__ __launch_bounds__(256) void fuse_mixed_cast(const float* __restrict__ inp,
    const float* __restrict__ attr, const float* __restrict__ pos,
    u16* __restrict__ mixed, u16* __restrict__ inpb, int n8) {
    int i = blockIdx.x * 256 + threadIdx.x;
    if (i >= n8) return;
    const f32x4* pi = (const f32x4*)(inp  + (size_t)i*8);
    const f32x4* pa = (const f32x4*)(attr + (size_t)i*8);
    const f32x4* pp = (const f32x4*)(pos  + (size_t)i*8);
    u16x8 om, oi;
    #pragma unroll
    for (int h = 0; h < 2; ++h) {
        f32x4 a = pi[h], b = pa[h], c = pp[h];
        #pragma unroll
        for (int j = 0; j < 4; ++j) {
            om[h*4+j] = f2bf(a[j] + b[j] + c[j]);
            oi[h*4+j] = f2bf(a[j]);
        }
    }
    *(u16x8*)(mixed + (size_t)i*8) = om;
    *(u16x8*)(inpb  + (size_t)i*8) = oi;
}

// ---------------------------------------------------------------------------
// Wt[y][n][k] = bf16(W_y[k][n])  (4 weights, 64x64 tiles via LDS)
__global__ __launch_bounds__(256) void transpose_w(const float* __restrict__ W0,
    const float* __restrict__ W1, const float* __restrict__ W2,
    const float* __restrict__ W3, u16* __restrict__ Wt) {
    const float* W = blockIdx.y==0 ? W0 : blockIdx.y==1 ? W1 : blockIdx.y==2 ? W2 : W3;
    u16* dst = Wt + (size_t)blockIdx.y*65536;
    int kt = blockIdx.x & 3, nt = blockIdx.x >> 2;
    __shared__ float T[64][65];
    int tid = threadIdx.x;
    int r = tid >> 2, cq = tid & 3;
    const float* src = W + (size_t)(kt*64 + r)*HH + nt*64 + cq*16;
    #pragma unroll
    for (int j = 0; j < 4; ++j) {
        f32x4 v = ((const f32x4*)src)[j];
        T[r][cq*16 + j*4 + 0] = v[0];
        T[r][cq*16 + j*4 + 1] = v[1];
        T[r][cq*16 + j*4 + 2] = v[2];
        T[r][cq*16 + j*4 + 3] = v[3];
    }
    __syncthreads();
    u16x8 o0, o1;
    #pragma unroll
    for (int j = 0; j < 8; ++j) o0[j] = f2bf(T[cq*16 + j][r]);
    #pragma unroll
    for (int j = 0; j < 8; ++j) o1[j] = f2bf(T[cq*16 + 8 + j][r]);
    u16* d = dst + (size_t)(nt*64 + r)*HH + kt*64 + cq*16;
    *(u16x8*)d       = o0;
    *(u16x8*)(d + 8) = o1;
}

// ---------------------------------------------------------------------------
// C[M,256] = A_bf16[M,256] @ W (Wt[n][k] bf16) + bias -> bf16 out
template<bool VT>
__global__ __launch_bounds__(256) void gemm_mfma(
    const u16* __restrict__ A0, const u16* __restrict__ A1,
    const u16* __restrict__ Wt, const float* __restrict__ bias0,
    const float* __restrict__ bias1, u16* __restrict__ O0, u16* __restrict__ O1)
{
    __shared__ u16 As[2][128*64];
    __shared__ u16 Ws[2][128*64];
    int tid = threadIdx.x;
    int w = tid >> 6, l = tid & 63;
    int lq = l & 15, g4 = l >> 4;
    int w0 = w >> 1, w1 = w & 1;
    int z = blockIdx.z;
    const u16* A = z ? A1 : A0;
    const u16* Wz = Wt + (size_t)z*65536;
    const float* bias = z ? bias1 : bias0;
    u16* Oz = z ? O1 : O0;
    int bm = blockIdx.x*128, bn = blockIdx.y*128;

    int rr0 = l >> 3;
    int cc0 = (l & 7) ^ (rr0 & 7);
    const u16* agp[4]; const u16* wgp[4];
    #pragma unroll
    for (int q = 0; q < 4; ++q) {
        int rr = (w*4+q)*8 + rr0;
        agp[q] = A  + (size_t)(bm + rr)*HH + cc0*8;
        wgp[q] = Wz + (size_t)(bn + rr)*HH + cc0*8;
    }

    f32x4 acc[4][4];
    #pragma unroll
    for (int i = 0; i < 4; ++i)
        #pragma unroll
        for (int j = 0; j < 4; ++j) acc[i][j] = (f32x4){0.f,0.f,0.f,0.f};

    #define STAGE(buf, k0) { \
        _Pragma("unroll") \
        for (int q = 0; q < 4; ++q) { \
            gload16(agp[q] + (k0), &As[buf][(w*4+q)*512]); \
            gload16(wgp[q] + (k0), &Ws[buf][(w*4+q)*512]); \
        } }

    STAGE(0, 0);
    __syncthreads();
    int cur = 0;
    #pragma unroll
    for (int t = 0; t < 4; ++t) {
        if (t < 3) STAGE(cur^1, (t+1)*64);
        #pragma unroll
        for (int kk = 0; kk < 2; ++kk) {
            bf16x8 af[4], wf[4];
            #pragma unroll
            for (int i = 0; i < 4; ++i) {
                int row = w0*64 + i*16 + lq;
                int cc = (kk*4 + g4) ^ (row & 7);
                af[i] = *(const bf16x8*)&As[cur][row*64 + cc*8];
            }
            #pragma unroll
            for (int j = 0; j < 4; ++j) {
                int row = w1*64 + j*16 + lq;
                int cc = (kk*4 + g4) ^ (row & 7);
                wf[j] = *(const bf16x8*)&Ws[cur][row*64 + cc*8];
            }
            #pragma unroll
            for (int i = 0; i < 4; ++i)
                #pragma unroll
                for (int j = 0; j < 4; ++j) {
                    if (VT)
                        acc[i][j] = __builtin_amdgcn_mfma_f32_16x16x32_bf16(af[i], wf[j], acc[i][j], 0,0,0);
                    else
                        acc[i][j] = __builtin_amdgcn_mfma_f32_16x16x32_bf16(wf[j], af[i], acc[i][j], 0,0,0);
                }
        }
        __syncthreads();
        cur ^= 1;
    }

    if (!VT) {
        #pragma unroll
        for (int i = 0; i < 4; ++i) {
            size_t m = bm + w0*64 + i*16 + lq;
            #pragma unroll
            for (int j = 0; j < 4; ++j) {
                int n = bn + w1*64 + j*16 + g4*4;
                f32x4 bb = *(const f32x4*)&bias[n];
                u16x4 o;
                #pragma unroll
                for (int r = 0; r < 4; ++r) o[r] = f2bf(acc[i][j][r] + bb[r]);
                *(u16x4*)&Oz[m*HH + n] = o;
            }
        }
    } else {
        int b = bm >> 11;
        int sb = bm & 2047;
        #pragma unroll
        for (int i = 0; i < 4; ++i) {
            int s = sb + w0*64 + i*16 + g4*4;
            #pragma unroll
            for (int j = 0; j < 4; ++j) {
                int n = bn + w1*64 + j*16 + lq;
                float bs = bias[n];
                int h = n >> 6, d = n & 63;
                u16x4 o;
                #pragma unroll
                for (int r = 0; r < 4; ++r) o[r] = f2bf(acc[i][j][r] + bs);
                *(u16x4*)&Oz[(((size_t)b*NHH + h)*DD + d)*SS + s] = o;
            }
        }
    }
    #undef STAGE
}

// ---------------------------------------------------------------------------
// Flash attention, bf16 MFMA 16x16x32, swapped-operand layout. ctx out bf16.
__global__ __launch_bounds__(512) void attn_mfma(
    const u16* __restrict__ Qb, const u16* __restrict__ Kb,
    const u16* __restrict__ Vt, const float* __restrict__ mask,
    u16* __restrict__ O)
{
    __shared__ u16 KT[2][64*64];
    __shared__ u16 VTs[2][64*64];
    __shared__ u16 PT[8][16*64];

    int tid = threadIdx.x;
    int w = tid >> 6, l = tid & 63;
    int lq = l & 15, g = l >> 4;
    int qb = blockIdx.x, h = blockIdx.y, b = blockIdx.z;
    int q = qb*128 + w*16 + lq;

    bf16x8 qf[2];
    {
        const u16* qp = Qb + ((size_t)(b*SS + q))*HH + h*DD + g*8;
        qf[0] = *(const bf16x8*)qp;
        qf[1] = *(const bf16x8*)(qp + 32);
    }

    int srow = tid >> 3;
    int sch  = tid & 7;
    const u16* kgp = Kb + ((size_t)(b*SS + srow))*HH + h*DD + sch*8;
    const u16* vgp = Vt + (((size_t)(b*NHH + h))*DD + srow)*SS + sch*8;
    int sidx = srow*64 + ((sch ^ (srow & 7)))*8;

    const float* mrow = mask + ((size_t)b*SS + q)*SS + g*4;

    f32x4 ot[4];
    #pragma unroll
    for (int dt = 0; dt < 4; ++dt) ot[dt] = (f32x4){0.f,0.f,0.f,0.f};
    float m = -1e30f, lsum = 0.f;

    u16x8 kr = *(const u16x8*)kgp;
    u16x8 vr = *(const u16x8*)vgp;
    f32x4 mra[4], mrb[4];
    #pragma unroll
    for (int kt = 0; kt < 4; ++kt) mra[kt] = *(const f32x4*)(mrow + kt*16);
    *(u16x8*)&KT[0][sidx]  = kr;
    *(u16x8*)&VTs[0][sidx] = vr;
    __syncthreads();

    #pragma unroll 2
    for (int t = 0; t < SS/64; ++t) {
        int cur = t & 1;
        if (t < SS/64 - 1) {
            kr = *(const u16x8*)(kgp + (size_t)(t+1)*64*HH);
            vr = *(const u16x8*)(vgp + (t+1)*64);
            #pragma unroll
            for (int kt = 0; kt < 4; ++kt)
                mrb[kt] = *(const f32x4*)(mrow + (t+1)*64 + kt*16);
        }

        // S^T = K @ Q^T
        f32x4 st[4];
        __builtin_amdgcn_s_setprio(1);
        #pragma unroll
        for (int kt = 0; kt < 4; ++kt) {
            st[kt] = (f32x4){0.f,0.f,0.f,0.f};
            int key = kt*16 + lq;
            #pragma unroll
            for (int df = 0; df < 2; ++df) {
                int c = (4*df + g) ^ (key & 7);
                bf16x8 a = *(const bf16x8*)&KT[cur][key*64 + c*8];
                st[kt] = __builtin_amdgcn_mfma_f32_16x16x32_bf16(a, qf[df], st[kt], 0,0,0);
            }
        }
        __builtin_amdgcn_s_setprio(0);

        // scores + mask
        float s[4][4];
        #pragma unroll
        for (int kt = 0; kt < 4; ++kt)
            #pragma unroll
            for (int j = 0; j < 4; ++j)
                s[kt][j] = __builtin_fmaf(st[kt][j], 0.125f, mra[kt][j]);

        // tile max (tree)
        float cm[4];
        #pragma unroll
        for (int kt = 0; kt < 4; ++kt)
            cm[kt] = fmaxf(fmaxf(s[kt][0], s[kt][1]), fmaxf(s[kt][2], s[kt][3]));
        float tm = fmaxf(fmaxf(cm[0], cm[1]), fmaxf(cm[2], cm[3]));
        tm = fmaxf(tm, __shfl_xor(tm, 16));
        tm = fmaxf(tm, __shfl_xor(tm, 32));

        // defer-max (T13): rescale only when tile max grew past threshold
        if (!__all(tm <= m + 8.0f)) {
            float mn = fmaxf(m, tm);
            float sc = fexp2((m - mn) * LOG2E);
            lsum *= sc;
            #pragma unroll
            for (int dt = 0; dt < 4; ++dt) {
                ot[dt][0] *= sc; ot[dt][1] *= sc;
                ot[dt][2] *= sc; ot[dt][3] *= sc;
            }
            m = mn;
        }
        float mnl = m * LOG2E;

        // exp (exp2-direct) + sum tree
        float e[4][4];
        #pragma unroll
        for (int kt = 0; kt < 4; ++kt)
            #pragma unroll
            for (int j = 0; j < 4; ++j)
                e[kt][j] = fexp2(__builtin_fmaf(s[kt][j], LOG2E, -mnl));
        float cs[4];
        #pragma unroll
        for (int kt = 0; kt < 4; ++kt)
            cs[kt] = (e[kt][0] + e[kt][1]) + (e[kt][2] + e[kt][3]);
        float rs = (cs[0] + cs[1]) + (cs[2] + cs[3]);
        rs += __shfl_xor(rs, 16);
        rs += __shfl_xor(rs, 32);
        lsum += rs;

        // pack P -> per-wave LDS (native casts, single 8B write)
        #pragma unroll
        for (int kt = 0; kt < 4; ++kt) {
            u16x4 pk;
            #pragma unroll
            for (int j = 0; j < 4; ++j) pk[j] = f2bf_n(e[kt][j]);
            int koff = kt*16 + g*4;
            int c = (koff >> 3) ^ (lq & 7);
            int idx = lq*64 + c*8 + (koff & 7);
            *(u16x4*)&PT[w][idx] = pk;
        }

        bf16x8 pb[2];
        #pragma unroll
        for (int kt2 = 0; kt2 < 2; ++kt2) {
            int c = (4*kt2 + g) ^ (lq & 7);
            pb[kt2] = *(const bf16x8*)&PT[w][lq*64 + c*8];
        }
        __builtin_amdgcn_s_setprio(1);
        #pragma unroll
        for (int dt = 0; dt < 4; ++dt) {
            int d = dt*16 + lq;
            #pragma unroll
            for (int kt2 = 0; kt2 < 2; ++kt2) {
                int c = (4*kt2 + g) ^ (d & 7);
                bf16x8 a = *(const bf16x8*)&VTs[cur][d*64 + c*8];
                ot[dt] = __builtin_amdgcn_mfma_f32_16x16x32_bf16(a, pb[kt2], ot[dt], 0,0,0);
            }
        }
        __builtin_amdgcn_s_setprio(0);

        if (t < SS/64 - 1) {
            *(u16x8*)&KT[cur^1][sidx]  = kr;
            *(u16x8*)&VTs[cur^1][sidx] = vr;
            #pragma unroll
            for (int kt = 0; kt < 4; ++kt) mra[kt] = mrb[kt];
        }
        __syncthreads();
    }

    float inv = 1.0f / lsum;
    #pragma unroll
    for (int dt = 0; dt < 4; ++dt) {
        u16x4 o;
        #pragma unroll
        for (int j = 0; j < 4; ++j) o[j] = f2bf_n(ot[dt][j] * inv);
        *(u16x4*)&O[((size_t)(b*SS + q))*HH + h*DD + dt*16 + g*4] = o;
    }
}

// ---------------------------------------------------------------------------
// out = LayerNorm(bf16 hidden + bf16 input) * gamma + beta
__global__ __launch_bounds__(256) void add_ln(const u16* __restrict__ hidden,
    const u16* __restrict__ inpb, const float* __restrict__ gamma,
    const float* __restrict__ beta, float* __restrict__ out) {
    int row = blockIdx.x;
    int tid = threadIdx.x;
    int lane = tid & 63, wave = tid >> 6;
    __shared__ float red[8];
    float x = bf2f(hidden[(size_t)row*HH + tid]) + bf2f(inpb[(size_t)row*HH + tid]);
    float s = x;
    #pragma unroll
    for (int o = 32; o; o >>= 1) s += __shfl_xor(s, o);
    if (!lane) red[wave] = s;
    __syncthreads();
    float mu = (red[0] + red[1] + red[2] + red[3]) * (1.0f/HH);
    float dx = x - mu;
    float v = dx * dx;
    #pragma unroll
    for (int o = 32; o; o >>= 1) v += __shfl_xor(v, o);
    if (!lane) red[4 + wave] = v;
    __syncthreads();
    float var = (red[4] + red[5] + red[6] + red[7]) * (1.0f/HH);
    out[(size_t)row*HH + tid] = dx * rsqrtf(var + 1e-12f) * gamma[tid] + beta[tid];
}

// ---------------------------------------------------------------------------
extern "C" void kernel_launch(void* const* d_in, const int* in_sizes, int n_in,
                              void* d_out, int out_size, void* d_ws, size_t ws_size,
                              hipStream_t stream) {
    const float* inp   = (const float*)d_in[0];
    const float* attr  = (const float*)d_in[1];
    const float* pos   = (const float*)d_in[2];
    const float* mask  = (const float*)d_in[3];
    const float* Wq    = (const float*)d_in[4];
    const float* bq    = (const float*)d_in[5];
    const float* Wk    = (const float*)d_in[6];
    const float* bk    = (const float*)d_in[7];
    const float* Wv    = (const float*)d_in[8];
    const float* bv    = (const float*)d_in[9];
    const float* Wd    = (const float*)d_in[10];
    const float* bd    = (const float*)d_in[11];
    const float* gamma = (const float*)d_in[12];
    const float* beta  = (const float*)d_in[13];
    float* out = (float*)d_out;

    const size_t NEL = (size_t)BB*SS*HH;   // 4,194,304
    u16* mixed = (u16*)d_ws;
    u16* inpb  = mixed + NEL;
    u16* Qb    = mixed + 2*NEL;
    u16* Kb    = mixed + 3*NEL;
    u16* Vtb   = mixed + 4*NEL;
    u16* ctx   = mixed + 5*NEL;
    u16* hid   = mixed + 6*NEL;
    u16* Wt    = mixed + 7*NEL;   // 4 x 65536 bf16

    fuse_mixed_cast<<<(int)(NEL/8/256), 256, 0, stream>>>(inp, attr, pos, mixed, inpb, (int)(NEL/8));
    transpose_w<<<dim3(16,4), 256, 0, stream>>>(Wq, Wk, Wv, Wd, Wt);

    gemm_mfma<false><<<dim3(128,2,2), 256, 0, stream>>>(mixed, mixed, Wt, bq, bk, Qb, Kb);
    gemm_mfma<true ><<<dim3(128,2,1), 256, 0, stream>>>(inpb, inpb, Wt + 2*65536, bv, bv, Vtb, Vtb);

    attn_mfma<<<dim3(SS/128, NHH, BB), 512, 0, stream>>>(Qb, Kb, Vtb, mask, ctx);

    gemm_mfma<false><<<dim3(128,2,1), 256, 0, stream>>>(ctx, ctx, Wt + 3*65536, bd, bd, hid, hid);

    add_ln<<<MROWS, 256, 0, stream>>>(hid, inpb, gamma, beta, out);
}